// Round 3
// baseline (221.739 us; speedup 1.0000x reference)
//
#include <hip/hip_runtime.h>
#include <math.h>

#define B_   16384
#define NP   6

// LDS layout (float offsets), peak 10624 floats = 42.5 KB
#define SW_OFF 0        // ph1 W tile   64 x 132            [0, 8448)
#define SA_OFF 8448     // ph1 A tile   32 x 68             [8448, 10624)
#define X1_OFF 0        // X1           32 x 100            [0, 3200)
#define W2_OFF 3328     // ph2 W chunk  32 x 96             [3328, 6400)
#define X2_OFF 6400     // X2           32 x 100            [6400, 9600)
#define W3_OFF 0        // ph3 W chunk  48 x 132            [0, 6336)
#define SMEMF  10624

__device__ __forceinline__ float gelu_f(float x) {
    return 0.5f * x * (1.0f + erff(x * 0.7071067811865476f));
}

// ---------------- kernel 1: needs + compaction + zero-fill dead rows ----------------
__global__ __launch_bounds__(256) void k_mask(
    const int* __restrict__ mask,
    float* __restrict__ out0, float* __restrict__ out1, float* __restrict__ out2,
    int* __restrict__ counts, int* __restrict__ lists)
{
    int p    = blockIdx.x >> 8;
    int tile = blockIdx.x & 255;
    int row0 = tile * 64;
    int t    = threadIdx.x;
    int src  = p >> 1;                       // 0,0,1,1,2,2
    int tgt  = (0x102021 >> (p * 4)) & 0xF;  // 1,2,0,2,0,1

    __shared__ int s_needs[64];
    if (t < 64) {
        int b  = row0 + t;
        int ms = mask[b * 3 + src];
        int mt = mask[b * 3 + tgt];
        int needs = (ms != 0) && (mt == 0);
        s_needs[t] = needs;
        unsigned long long bal = __ballot(needs);
        int total = __popcll(bal);
        int base = 0;
        if (t == 0 && total) base = atomicAdd(&counts[p], total);
        base = __shfl(base, 0, 64);
        if (needs) {
            int prefix = __popcll(bal & ((1ull << t) - 1ull));
            lists[p * B_ + base + prefix] = b;
        }
    }
    __syncthreads();

    int wave = t >> 6, lane = t & 63;
    float4 z = make_float4(0.f, 0.f, 0.f, 0.f);
    for (int r = wave; r < 64; r += 4) {
        if (!s_needs[r]) {
            size_t rowoff = ((size_t)(p * B_ + row0 + r)) * 256 + lane * 4;
            *(float4*)(out0 + rowoff) = z;
            *(float4*)(out1 + rowoff) = z;
        }
    }
    if (t < 64 && !s_needs[t]) out2[p * B_ + row0 + t] = 0.f;
}

// ---------------- kernel 2: fused MLP over compacted rows (32-row tiles) ----------------
__global__ __launch_bounds__(256, 3) void k_main(
    const float* __restrict__ mus, const float* __restrict__ logvars,
    const float* __restrict__ hw1, const float* __restrict__ hb1,
    const float* __restrict__ hg1, const float* __restrict__ hbe1,
    const float* __restrict__ hw2, const float* __restrict__ hb2,
    const float* __restrict__ hg2, const float* __restrict__ hbe2,
    const float* __restrict__ hw3, const float* __restrict__ hb3,
    const float* __restrict__ gw1, const float* __restrict__ gb1,
    const float* __restrict__ gg1, const float* __restrict__ gbe1,
    const float* __restrict__ gw2, const float* __restrict__ gb2,
    const int* __restrict__ counts, const int* __restrict__ lists,
    float* __restrict__ out0, float* __restrict__ out1, float* __restrict__ out2)
{
    int p     = blockIdx.x >> 9;
    int tile  = blockIdx.x & 511;
    int cnt   = counts[p];
    int start = tile * 32;
    if (start >= cnt) return;
    int nr = min(32, cnt - start);

    __shared__ int   s_rows[32];
    __shared__ float smem[SMEMF];

    int t = threadIdx.x;
    if (t < 32) s_rows[t] = lists[p * B_ + start + min(t, nr - 1)];
    __syncthreads();

    int tx = t & 15, ty = t >> 4;
    int r0 = ty * 2, r1 = r0 + 1;

    const float* Ab  = mus     + (size_t)(p >> 1) * B_ * 256;
    const float* Lb  = logvars + (size_t)(p >> 1) * B_ * 256;
    const float* w1p = hw1 + (size_t)p * 512 * 96;
    const float* g1p = gw1 + (size_t)p * 512 * 32;
    const float* w2p = hw2 + (size_t)p * 96 * 96;
    const float* w3p = hw3 + (size_t)p * 96 * 512;

    // ================= phase 1: acc[2][8] = h(32x512) @ [hw1|gw1](512x128) =================
    float acc[2][8];
#pragma unroll
    for (int m = 0; m < 2; ++m)
#pragma unroll
        for (int n = 0; n < 8; ++n) acc[m][n] = 0.f;

    int arow = t >> 3, ac = (t & 7) * 8;      // A staging: 32 rows x 64 k
    int wrow = t >> 2, wc0 = (t & 3) * 4;     // W staging: 64 rows

    for (int kt = 0; kt < 8; ++kt) {
        int k0   = kt * 64;
        const float* srcb = (kt < 4) ? Ab : Lb;
        int koff = k0 & 255;

        __syncthreads();
        {   // A tile 32x64 (stride 68)
            const float* g = srcb + (size_t)s_rows[arow] * 256 + koff + ac;
            float4 v0 = *(const float4*)g;
            float4 v1 = *(const float4*)(g + 4);
            float* d = smem + SA_OFF + arow * 68 + ac;
            *(float4*)d       = v0;
            *(float4*)(d + 4) = v1;
        }
        {   // W tile 64x(96|32) (stride 132)
#pragma unroll
            for (int j = 0; j < 6; ++j) {
                int c = wc0 + j * 16;
                *(float4*)(smem + SW_OFF + wrow * 132 + c) =
                    *(const float4*)(w1p + (size_t)(k0 + wrow) * 96 + c);
            }
#pragma unroll
            for (int j = 0; j < 2; ++j) {
                int c = wc0 + j * 16;
                *(float4*)(smem + SW_OFF + wrow * 132 + 96 + c) =
                    *(const float4*)(g1p + (size_t)(k0 + wrow) * 32 + c);
            }
        }
        __syncthreads();

        const float* A0 = smem + SA_OFF + r0 * 68;
        const float* A1 = smem + SA_OFF + r1 * 68;
        const float* Wb = smem + SW_OFF + tx * 8;
#pragma unroll 4
        for (int kk = 0; kk < 64; ++kk) {
            float a0 = A0[kk], a1 = A1[kk];
            const float* wr = Wb + kk * 132;
            float4 w0 = *(const float4*)wr;
            float4 w1 = *(const float4*)(wr + 4);
            acc[0][0] = fmaf(a0, w0.x, acc[0][0]); acc[1][0] = fmaf(a1, w0.x, acc[1][0]);
            acc[0][1] = fmaf(a0, w0.y, acc[0][1]); acc[1][1] = fmaf(a1, w0.y, acc[1][1]);
            acc[0][2] = fmaf(a0, w0.z, acc[0][2]); acc[1][2] = fmaf(a1, w0.z, acc[1][2]);
            acc[0][3] = fmaf(a0, w0.w, acc[0][3]); acc[1][3] = fmaf(a1, w0.w, acc[1][3]);
            acc[0][4] = fmaf(a0, w1.x, acc[0][4]); acc[1][4] = fmaf(a1, w1.x, acc[1][4]);
            acc[0][5] = fmaf(a0, w1.y, acc[0][5]); acc[1][5] = fmaf(a1, w1.y, acc[1][5]);
            acc[0][6] = fmaf(a0, w1.z, acc[0][6]); acc[1][6] = fmaf(a1, w1.z, acc[1][6]);
            acc[0][7] = fmaf(a0, w1.w, acc[0][7]); acc[1][7] = fmaf(a1, w1.w, acc[1][7]);
        }
    }
    __syncthreads();   // protect SW/SA before X1 overwrites

    // ====== LN1 + gelu via 16-lane shuffles; gate branch fully fused ======
    // row r (= 2ty+m) columns: tx*8..tx*8+7; tx<12 -> h branch (96), tx>=12 -> gate (32)
#pragma unroll
    for (int m = 0; m < 2; ++m) {
        int r = r0 + m;
        float v[8];
#pragma unroll
        for (int n = 0; n < 8; ++n) {
            int c = tx * 8 + n;
            float bias = (tx < 12) ? hb1[p * 96 + c] : gb1[p * 32 + (c - 96)];
            v[n] = acc[m][n] + bias;
        }
        // --- h-branch LN over 96 cols ---
        float ls = 0.f;
#pragma unroll
        for (int n = 0; n < 8; ++n) ls += v[n];
        float hs = (tx < 12) ? ls : 0.f;
#pragma unroll
        for (int mk = 8; mk; mk >>= 1) hs += __shfl_xor(hs, mk, 16);
        float mean = hs * (1.f / 96.f);
        float sq = 0.f;
#pragma unroll
        for (int n = 0; n < 8; ++n) { float d = v[n] - mean; sq += d * d; }
        float hq = (tx < 12) ? sq : 0.f;
#pragma unroll
        for (int mk = 8; mk; mk >>= 1) hq += __shfl_xor(hq, mk, 16);
        float rs = rsqrtf(hq * (1.f / 96.f) + 1e-5f);
        if (tx < 12) {
            float xo[8];
#pragma unroll
            for (int n = 0; n < 8; ++n) {
                int c = tx * 8 + n;
                xo[n] = gelu_f((v[n] - mean) * rs * hg1[p * 96 + c] + hbe1[p * 96 + c]);
            }
            float* d = smem + X1_OFF + r * 100 + tx * 8;
            *(float4*)d       = make_float4(xo[0], xo[1], xo[2], xo[3]);
            *(float4*)(d + 4) = make_float4(xo[4], xo[5], xo[6], xo[7]);
        } else {
            // --- gate branch: LN over 32 cols (lanes tx=12..15), gelu, dot gw2, sigmoid ---
            float gs = ls;
            gs += __shfl_xor(gs, 1, 16); gs += __shfl_xor(gs, 2, 16);
            float mg = gs * (1.f / 32.f);
            float gq = 0.f;
#pragma unroll
            for (int n = 0; n < 8; ++n) { float d = v[n] - mg; gq += d * d; }
            gq += __shfl_xor(gq, 1, 16); gq += __shfl_xor(gq, 2, 16);
            float rsg = rsqrtf(gq * (1.f / 32.f) + 1e-5f);
            float gv = 0.f;
#pragma unroll
            for (int n = 0; n < 8; ++n) {
                int cg = tx * 8 + n - 96;
                gv += gelu_f((v[n] - mg) * rsg * gg1[p * 32 + cg] + gbe1[p * 32 + cg]) * gw2[p * 32 + cg];
            }
            gv += __shfl_xor(gv, 1, 16); gv += __shfl_xor(gv, 2, 16);
            if (tx == 12 && r < nr)
                out2[p * B_ + s_rows[r]] = 1.f / (1.f + expf(-(gv + gb2[p])));
        }
    }

    // ================= phase 2: acc2[2][6] = X1(32x96) @ hw2(96x96) =================
    float acc2[2][6];
#pragma unroll
    for (int m = 0; m < 2; ++m)
#pragma unroll
        for (int n = 0; n < 6; ++n) acc2[m][n] = 0.f;

    int r2 = t >> 3, c20 = (t & 7) * 4;
    for (int c3 = 0; c3 < 3; ++c3) {
        __syncthreads();
#pragma unroll
        for (int j = 0; j < 3; ++j) {   // stage 32x96 chunk of W2
            int c = c20 + j * 32;
            *(float4*)(smem + W2_OFF + r2 * 96 + c) =
                *(const float4*)(w2p + (size_t)(c3 * 32 + r2) * 96 + c);
        }
        __syncthreads();
        const float* A0 = smem + X1_OFF + r0 * 100 + c3 * 32;
        const float* A1 = smem + X1_OFF + r1 * 100 + c3 * 32;
        const float* Wb = smem + W2_OFF + tx * 6;
#pragma unroll 4
        for (int kk = 0; kk < 32; ++kk) {
            float a0 = A0[kk], a1 = A1[kk];
            const float* wr = Wb + kk * 96;
            float w0 = wr[0], w1 = wr[1], w2 = wr[2], w3 = wr[3], w4 = wr[4], w5 = wr[5];
            acc2[0][0] = fmaf(a0, w0, acc2[0][0]); acc2[1][0] = fmaf(a1, w0, acc2[1][0]);
            acc2[0][1] = fmaf(a0, w1, acc2[0][1]); acc2[1][1] = fmaf(a1, w1, acc2[1][1]);
            acc2[0][2] = fmaf(a0, w2, acc2[0][2]); acc2[1][2] = fmaf(a1, w2, acc2[1][2]);
            acc2[0][3] = fmaf(a0, w3, acc2[0][3]); acc2[1][3] = fmaf(a1, w3, acc2[1][3]);
            acc2[0][4] = fmaf(a0, w4, acc2[0][4]); acc2[1][4] = fmaf(a1, w4, acc2[1][4]);
            acc2[0][5] = fmaf(a0, w5, acc2[0][5]); acc2[1][5] = fmaf(a1, w5, acc2[1][5]);
        }
    }

    // ====== LN2 + gelu via shuffles -> X2 (cols tx*6..+5, exactly 96) ======
#pragma unroll
    for (int m = 0; m < 2; ++m) {
        int r = r0 + m;
        float v[6];
#pragma unroll
        for (int n = 0; n < 6; ++n) v[n] = acc2[m][n] + hb2[p * 96 + tx * 6 + n];
        float hs = v[0] + v[1] + v[2] + v[3] + v[4] + v[5];
#pragma unroll
        for (int mk = 8; mk; mk >>= 1) hs += __shfl_xor(hs, mk, 16);
        float mean = hs * (1.f / 96.f);
        float sq = 0.f;
#pragma unroll
        for (int n = 0; n < 6; ++n) { float d = v[n] - mean; sq += d * d; }
#pragma unroll
        for (int mk = 8; mk; mk >>= 1) sq += __shfl_xor(sq, mk, 16);
        float rs = rsqrtf(sq * (1.f / 96.f) + 1e-5f);
        float* d = smem + X2_OFF + r * 100 + tx * 6;
#pragma unroll
        for (int n = 0; n < 6; ++n) {
            int c = tx * 6 + n;
            d[n] = gelu_f((v[n] - mean) * rs * hg2[p * 96 + c] + hbe2[p * 96 + c]);
        }
    }

    // ================= phase 3: out(32x512) = X2(32x96) @ hw3(96x512) =================
    for (int cp = 0; cp < 4; ++cp) {
        float acc3[2][8];
#pragma unroll
        for (int m = 0; m < 2; ++m)
#pragma unroll
            for (int n = 0; n < 8; ++n) acc3[m][n] = 0.f;

        for (int kc = 0; kc < 2; ++kc) {
            __syncthreads();
#pragma unroll
            for (int j = 0; j < 6; ++j) {   // stage 48 x 128 chunk of W3 (stride 132)
                int idx = t + j * 256;
                int row = idx >> 5, c = (idx & 31) * 4;
                *(float4*)(smem + W3_OFF + row * 132 + c) =
                    *(const float4*)(w3p + (size_t)(kc * 48 + row) * 512 + cp * 128 + c);
            }
            __syncthreads();
            const float* A0 = smem + X2_OFF + r0 * 100 + kc * 48;
            const float* A1 = smem + X2_OFF + r1 * 100 + kc * 48;
            const float* Wb = smem + W3_OFF + tx * 8;
#pragma unroll 4
            for (int kk = 0; kk < 48; ++kk) {
                float a0 = A0[kk], a1 = A1[kk];
                const float* wr = Wb + kk * 132;
                float4 w0 = *(const float4*)wr;
                float4 w1 = *(const float4*)(wr + 4);
                acc3[0][0] = fmaf(a0, w0.x, acc3[0][0]); acc3[1][0] = fmaf(a1, w0.x, acc3[1][0]);
                acc3[0][1] = fmaf(a0, w0.y, acc3[0][1]); acc3[1][1] = fmaf(a1, w0.y, acc3[1][1]);
                acc3[0][2] = fmaf(a0, w0.z, acc3[0][2]); acc3[1][2] = fmaf(a1, w0.z, acc3[1][2]);
                acc3[0][3] = fmaf(a0, w0.w, acc3[0][3]); acc3[1][3] = fmaf(a1, w0.w, acc3[1][3]);
                acc3[0][4] = fmaf(a0, w1.x, acc3[0][4]); acc3[1][4] = fmaf(a1, w1.x, acc3[1][4]);
                acc3[0][5] = fmaf(a0, w1.y, acc3[0][5]); acc3[1][5] = fmaf(a1, w1.y, acc3[1][5]);
                acc3[0][6] = fmaf(a0, w1.z, acc3[0][6]); acc3[1][6] = fmaf(a1, w1.z, acc3[1][6]);
                acc3[0][7] = fmaf(a0, w1.w, acc3[0][7]); acc3[1][7] = fmaf(a1, w1.w, acc3[1][7]);
            }
        }

        int c = cp * 128 + tx * 8;
#pragma unroll
        for (int m = 0; m < 2; ++m) {
            int r = r0 + m;
            if (r < nr) {
                int b = s_rows[r];
                size_t rb = ((size_t)(p * B_ + b)) * 256;
                float o[8];
#pragma unroll
                for (int n = 0; n < 8; ++n) o[n] = acc3[m][n] + hb3[p * 512 + c + n];
                if (cp < 2) {
                    *(float4*)(out0 + rb + c)     = make_float4(o[0], o[1], o[2], o[3]);
                    *(float4*)(out0 + rb + c + 4) = make_float4(o[4], o[5], o[6], o[7]);
                } else {
#pragma unroll
                    for (int n = 0; n < 8; ++n) o[n] = fminf(fmaxf(o[n], -6.f), 2.f);
                    size_t cc = rb + (c - 256);
                    *(float4*)(out1 + cc)     = make_float4(o[0], o[1], o[2], o[3]);
                    *(float4*)(out1 + cc + 4) = make_float4(o[4], o[5], o[6], o[7]);
                }
            }
        }
    }
}

extern "C" void kernel_launch(void* const* d_in, const int* in_sizes, int n_in,
                              void* d_out, int out_size, void* d_ws, size_t ws_size,
                              hipStream_t stream)
{
    (void)in_sizes; (void)n_in; (void)out_size; (void)ws_size;

    const float* mus     = (const float*)d_in[0];
    const float* logvars = (const float*)d_in[1];
    const int*   mask    = (const int*)d_in[2];   // numpy bool -> int32 per harness
    const float* hw1  = (const float*)d_in[3];
    const float* hb1  = (const float*)d_in[4];
    const float* hg1  = (const float*)d_in[5];
    const float* hbe1 = (const float*)d_in[6];
    const float* hw2  = (const float*)d_in[7];
    const float* hb2  = (const float*)d_in[8];
    const float* hg2  = (const float*)d_in[9];
    const float* hbe2 = (const float*)d_in[10];
    const float* hw3  = (const float*)d_in[11];
    const float* hb3  = (const float*)d_in[12];
    const float* gw1  = (const float*)d_in[13];
    const float* gb1  = (const float*)d_in[14];
    const float* gg1  = (const float*)d_in[15];
    const float* gbe1 = (const float*)d_in[16];
    const float* gw2  = (const float*)d_in[17];
    const float* gb2  = (const float*)d_in[18];

    float* out0 = (float*)d_out;
    float* out1 = out0 + (size_t)NP * B_ * 256;
    float* out2 = out1 + (size_t)NP * B_ * 256;

    int* counts = (int*)d_ws;
    int* lists  = counts + 64;

    hipMemsetAsync(d_ws, 0, 64 * sizeof(int), stream);
    k_mask<<<dim3(NP * 256), dim3(256), 0, stream>>>(mask, out0, out1, out2, counts, lists);
    k_main<<<dim3(NP * 512), dim3(256), 0, stream>>>(
        mus, logvars, hw1, hb1, hg1, hbe1, hw2, hb2, hg2, hbe2, hw3, hb3,
        gw1, gb1, gg1, gbe1, gw2, gb2, counts, lists, out0, out1, out2);
}